// Round 4
// baseline (370.612 us; speedup 1.0000x reference)
//
#include <hip/hip_runtime.h>
#include <hip/hip_bf16.h>
#include <math.h>

#define B 64
#define N 512
#define C 1024
#define K_NEIGH 32
// band half-width: DELTA - bisect_window/2 - E > E with E ~ 0.15 (9-sigma
// fp16-hi GEMM error bound), window = 2800/2^14 = 0.17. Band entries get an
// exact fp32 recheck; non-band entries are provably on the correct side.
#define DELTA 0.625f
#define BISECT_ITERS 14
#define NITER (C / 32)

typedef __attribute__((ext_vector_type(8))) _Float16 half8;
typedef __attribute__((ext_vector_type(4))) float f32x4;

__device__ inline half8 cvt16(float4 f0, float4 f1) {
    half8 g;
    g[0] = (_Float16)f0.x; g[1] = (_Float16)f0.y; g[2] = (_Float16)f0.z; g[3] = (_Float16)f0.w;
    g[4] = (_Float16)f1.x; g[5] = (_Float16)f1.y; g[6] = (_Float16)f1.z; g[7] = (_Float16)f1.w;
    return g;
}

// ---------------------------------------------------------------------------
// Kernel 1: S'[b] = fp16(x[b]) * fp16(x[b])^T via f16 MFMA.
// Full 16 strip-pairs (no mirror store) -> grid 64x16 = 1024 blocks.
// 128x128 tile, 256 thr = 4 waves (64x64 each = 4x4 of 16x16x32).
// Software pipeline: prefetch global loads for k+1 at loop top; MFMA on
// LDS buf p; cvt+ds_write k+1 into buf p^1; ONE barrier per iter.
// LDS granule layout: index s*128+row holds 8 fp16 of k=s*8 for that row.
// A-frag: A[m=lane&15][k=(lane>>4)*8+j]; C/D: col=lane&15, row=(lane>>4)*4+reg
// ---------------------------------------------------------------------------
__global__ __launch_bounds__(256) void gemm_f16(const float* __restrict__ x,
                                                float* __restrict__ S) {
    __shared__ half8 Abuf[2][512], Bbuf[2][512];   // 2 x (8KB + 8KB) = 32 KB

    const int b  = blockIdx.x;
    const int ti = blockIdx.y >> 2;
    const int tj = blockIdx.y & 3;
    const int row0A = ti * 128;
    const int row0B = tj * 128;
    const float* xb = x + (size_t)b * N * C;

    const int t    = threadIdx.x;
    const int w    = t >> 6;
    const int lane = t & 63;
    const int quad = lane >> 4;
    const int lid  = lane & 15;
    const int wr   = (w >> 1) * 64;
    const int wc   = (w & 1) * 64;

    // staging: thread t -> row (t>>1), k-quarter (t&1)*16 (granules sg, sg+1)
    const int srow = t >> 1;
    const int sg   = (t & 1) * 2;
    const float* pA = xb + (size_t)(row0A + srow) * C + sg * 8;
    const float* pB = xb + (size_t)(row0B + srow) * C + sg * 8;

    f32x4 acc[4][4];
#pragma unroll
    for (int r = 0; r < 4; r++)
#pragma unroll
        for (int c = 0; c < 4; c++)
#pragma unroll
            for (int e = 0; e < 4; e++) acc[r][c][e] = 0.f;

    float4 fa[4], fb[4];
    // prologue: load + stage iter 0 into buf 0
    {
        const float4* qa = (const float4*)pA;
        const float4* qb = (const float4*)pB;
#pragma unroll
        for (int i = 0; i < 4; i++) { fa[i] = qa[i]; fb[i] = qb[i]; }
        Abuf[0][sg * 128 + srow]       = cvt16(fa[0], fa[1]);
        Abuf[0][(sg + 1) * 128 + srow] = cvt16(fa[2], fa[3]);
        Bbuf[0][sg * 128 + srow]       = cvt16(fb[0], fb[1]);
        Bbuf[0][(sg + 1) * 128 + srow] = cvt16(fb[2], fb[3]);
    }
    __syncthreads();

    int p = 0;
    for (int kt = 0; kt < NITER; kt++) {
        if (kt + 1 < NITER) {   // issue next iter's global loads early
            const float4* qa = (const float4*)(pA + (kt + 1) * 32);
            const float4* qb = (const float4*)(pB + (kt + 1) * 32);
#pragma unroll
            for (int i = 0; i < 4; i++) { fa[i] = qa[i]; fb[i] = qb[i]; }
        }

        half8 vb[4];
#pragma unroll
        for (int c = 0; c < 4; c++) vb[c] = Bbuf[p][quad * 128 + wc + c * 16 + lid];
#pragma unroll
        for (int r = 0; r < 4; r++) {
            half8 va = Abuf[p][quad * 128 + wr + r * 16 + lid];
#pragma unroll
            for (int c = 0; c < 4; c++)
                acc[r][c] = __builtin_amdgcn_mfma_f32_16x16x32_f16(va, vb[c], acc[r][c], 0, 0, 0);
        }

        if (kt + 1 < NITER) {   // stage k+1 into the other buffer
            const int q = p ^ 1;
            Abuf[q][sg * 128 + srow]       = cvt16(fa[0], fa[1]);
            Abuf[q][(sg + 1) * 128 + srow] = cvt16(fa[2], fa[3]);
            Bbuf[q][sg * 128 + srow]       = cvt16(fb[0], fb[1]);
            Bbuf[q][(sg + 1) * 128 + srow] = cvt16(fb[2], fb[3]);
        }
        __syncthreads();
        p ^= 1;
    }

    float* Sb = S + (size_t)b * N * N;
#pragma unroll
    for (int r = 0; r < 4; r++) {
#pragma unroll
        for (int c = 0; c < 4; c++) {
#pragma unroll
            for (int e = 0; e < 4; e++) {
                const int grow = row0A + wr + r * 16 + quad * 4 + e;
                const int gcol = row0B + wc + c * 16 + lid;
                Sb[(size_t)grow * N + gcol] = acc[r][c][e];
            }
        }
    }
}

// ---------------------------------------------------------------------------
// Kernel 2: per row -- ballot-popcount bisection for pivot P; band [P-d,P+d]
// rechecked with wave-cooperative exact fp32 dots; exact threshold among
// band; emit 512-bit adjacency mask + deg^-0.5. One wave/row, 4 rows/block.
// Lane l holds cols l*8..l*8+7 (float4-coalesced; ballots count any layout).
// ---------------------------------------------------------------------------
__global__ __launch_bounds__(256) void thresh_mask(const float* __restrict__ S,
                                                   const float* __restrict__ x,
                                                   unsigned long long* __restrict__ masks,
                                                   float* __restrict__ dinv) {
    const int row  = blockIdx.x * 4 + (threadIdx.x >> 6);
    const int lane = threadIdx.x & 63;
    const float* Srow = S + (size_t)row * N;

    float4 a0 = ((const float4*)Srow)[lane * 2];
    float4 a1 = ((const float4*)Srow)[lane * 2 + 1];
    float v0[8] = {a0.x, a0.y, a0.z, a0.w, a1.x, a1.y, a1.z, a1.w};

    // bisection: invariant cnt(lo) >= 32, cnt(hi) <= 31, cnt(p) = #{v > p}
    float lo = -1400.f, hi = 1400.f;
    for (int it = 0; it < BISECT_ITERS; it++) {
        const float mid = 0.5f * (lo + hi);
        int c = 0;
#pragma unroll
        for (int k = 0; k < 8; k++) c += __popcll(__ballot(v0[k] > mid));
        if (c >= K_NEIGH) lo = mid; else hi = mid;
    }
    const float P   = 0.5f * (lo + hi);
    const float hiB = P + DELTA, loB = P - DELTA;

    int cA = 0;
#pragma unroll
    for (int k = 0; k < 8; k++) cA += __popcll(__ballot(v0[k] > hiB));
    const int m_need = K_NEIGH - cA;   // >= 1

    // band candidates: one per lane; col of (bit bl, slot k) = bl*8 + k
    int cnt = 0, myj = -1;
#pragma unroll
    for (int kq = 0; kq < 8; kq++) {
        unsigned long long bm = __ballot(v0[kq] >= loB && v0[kq] <= hiB);
        while (bm) {
            int bl = __ffsll(bm) - 1;
            bm &= bm - 1;
            if (cnt == lane) myj = bl * 8 + kq;
            cnt++;
        }
    }
    const int nc = cnt < 64 ? cnt : 64;

    // wave-cooperative exact fp32 dots for band candidates
    const int bb_ = row >> 9, ii = row & (N - 1);
    const float* xi = x + ((size_t)bb_ * N + ii) * C;
    float4 ai[4];
#pragma unroll
    for (int q = 0; q < 4; q++) ai[q] = *(const float4*)(xi + q * 256 + lane * 4);

    float ex = -INFINITY;
    for (int c2 = 0; c2 < nc; c2++) {
        const int j = __shfl(myj, c2);
        const float* xj = x + ((size_t)bb_ * N + j) * C;
        float s = 0.f;
#pragma unroll
        for (int q = 0; q < 4; q++) {
            float4 bv = *(const float4*)(xj + q * 256 + lane * 4);
            s = fmaf(ai[q].x, bv.x, s);
            s = fmaf(ai[q].y, bv.y, s);
            s = fmaf(ai[q].z, bv.z, s);
            s = fmaf(ai[q].w, bv.w, s);
        }
#pragma unroll
        for (int off = 32; off > 0; off >>= 1) s += __shfl_xor(s, off);
        if (lane == c2) ex = s;   // deterministic per (i,j)
    }

    // exact threshold T = m_need-th largest band value (tie-correct)
    float val = ex, T = -INFINITY;
    for (int it = 0; it < m_need; it++) {
        float M = val;
#pragma unroll
        for (int off = 32; off > 0; off >>= 1) M = fmaxf(M, __shfl_xor(M, off));
        T = M;
        unsigned long long ball = __ballot(val == M);
        int first = __ffsll(ball) - 1;
        if (lane == first) val = -INFINITY;
    }
    const int dec = (lane < nc && ex >= T) ? 1 : 0;

    // per-lane byte: certain-above -> 1; band -> exact decision (disjoint sets)
    unsigned byte = 0;
#pragma unroll
    for (int k = 0; k < 8; k++) byte |= (v0[k] > hiB) ? (1u << k) : 0u;
    for (int c2 = 0; c2 < nc; c2++) {
        int j = __shfl(myj, c2);
        int d = __shfl(dec, c2);
        if ((j >> 3) == lane) byte |= (unsigned)d << (j & 7);
    }

    // assemble u64 words from groups of 8 lanes; or-reduce within group
    unsigned long long part = (unsigned long long)byte << ((lane & 7) * 8);
    part |= __shfl_xor(part, 1);
    part |= __shfl_xor(part, 2);
    part |= __shfl_xor(part, 4);

    int deg = __popc(byte);
#pragma unroll
    for (int off = 32; off > 0; off >>= 1) deg += __shfl_xor(deg, off);

    if ((lane & 7) == 0) masks[(size_t)row * 8 + (lane >> 3)] = part;
    if (lane == 0) dinv[row] = rsqrtf((float)deg);
}

// ---------------------------------------------------------------------------
// Kernel 3: out[b,i,j] = maskbit ? dinv[b,i]*dinv[b,j] : 0  (writes over S')
// ---------------------------------------------------------------------------
__global__ __launch_bounds__(256) void scale_adj(float* __restrict__ Sout,
                                                 const unsigned long long* __restrict__ masks,
                                                 const float* __restrict__ dinv) {
    const int idx = blockIdx.x * 256 + threadIdx.x;   // float4 index
    const int jq = idx & 127;
    const int i  = (idx >> 7) & (N - 1);
    const int b  = idx >> 16;
    const int row = (b << 9) | i;
    const int j0 = jq * 4;

    const unsigned long long mk = masks[(size_t)row * 8 + (j0 >> 6)];
    const float di = dinv[row];
    float4 dj = ((const float4*)dinv)[(b << 7) | jq];

    float4 o;
    o.x = ((mk >> ((j0 + 0) & 63)) & 1ull) ? di * dj.x : 0.f;
    o.y = ((mk >> ((j0 + 1) & 63)) & 1ull) ? di * dj.y : 0.f;
    o.z = ((mk >> ((j0 + 2) & 63)) & 1ull) ? di * dj.z : 0.f;
    o.w = ((mk >> ((j0 + 3) & 63)) & 1ull) ? di * dj.w : 0.f;
    ((float4*)Sout)[idx] = o;
}

// ---------------------------------------------------------------------------
extern "C" void kernel_launch(void* const* d_in, const int* in_sizes, int n_in,
                              void* d_out, int out_size, void* d_ws, size_t ws_size,
                              hipStream_t stream) {
    const float* x = (const float*)d_in[0];
    float* out = (float*)d_out;                      // stages S', then final out
    unsigned long long* masks = (unsigned long long*)d_ws;     // B*N*8 u64 = 2MB
    float* dinv = (float*)(masks + (size_t)B * N * 8);         // B*N floats

    dim3 g1(B, 16);                                  // all strip pairs
    gemm_f16<<<g1, 256, 0, stream>>>(x, out);
    thresh_mask<<<B * N / 4, 256, 0, stream>>>(out, x, masks, dinv);
    const int total4 = B * N * N / 4;
    scale_adj<<<total4 / 256, 256, 0, stream>>>(out, masks, dinv);
}